// Round 2
// baseline (3666.856 us; speedup 1.0000x reference)
//
#include <hip/hip_runtime.h>

// spatialAttentionScaledGCN — MI355X, all-fp32 I/O (per reference), fp16-packed LDS X.
// B=8, N=512, T=12, F_IN=32, F_OUT=64.
// 11 Jacobi iterations: per (b,t>=1): S = Xt·Xt^T/sqrt(32), row-softmax,
// x_pred = (phase .* sa)^T · X_{t-1}, mask blend. Final: phase*adj*sa agg over m,
// then relu(agg·theta), output transposed to (B,N,T,O) as fp32.

#define B_ 8
#define N_ 512
#define T_ 12
#define F_ 32
#define O_ 64

#define MT 8                  // m-tiles per (b,t)
#define MROWS (N_ / MT)       // 64 softmax rows per block
#define CH 8                  // rows per score chunk (LDS-resident)
#define NCHUNK (MROWS / CH)   // 8
#define PAD_S 513             // Sch row pad (floats)

typedef unsigned int uint_t;
typedef _Float16 f16_t;
typedef f16_t f16x2 __attribute__((ext_vector_type(2)));

__device__ __forceinline__ f16x2 u2h(uint_t u) { union { uint_t i; f16x2 h; } v; v.i = u; return v.h; }
__device__ __forceinline__ uint_t packh2(float lo, float hi) {
    union { f16x2 h; uint_t i; } v;
    v.h[0] = (f16_t)lo; v.h[1] = (f16_t)hi;
    return v.i;
}
__device__ __forceinline__ void atomAddF(float* p, float v) {
    __hip_atomic_fetch_add(p, v, __ATOMIC_RELAXED, __HIP_MEMORY_SCOPE_AGENT);
}
__device__ __forceinline__ int xidx(int b, int n, int t, int f) {
    return ((b * N_ + n) * T_ + t) * F_ + f;
}

// One fixed-point iteration. Block = (m-tile mt, time t=1..11, batch b).
// Accumulates partial x_pred over its 64 softmax rows; atomic-reduces into
// zeroed xnext for unmasked nodes; mt==0 block writes masked passthrough.
__global__ __launch_bounds__(256)
void iter_kernel(const float* __restrict__ x0,     // original input x (time-0 / first prev)
                 const float* __restrict__ xcur,
                 float* __restrict__ xnext,        // pre-zeroed
                 const float* __restrict__ phase,
                 const float* __restrict__ mask)
{
    __shared__ uint_t Xt[N_][17];                  // all 512 rows, fp16-packed pairs (+1 pad)
    __shared__ float Sch[CH][PAD_S];               // score/weight chunk
    __shared__ alignas(16) float Xp[CH][F_];       // prev-time rows for this chunk
    __shared__ float smax[CH];
    __shared__ float srcp[CH];

    const int tid = threadIdx.x;
    const int mt  = blockIdx.x;
    const int t   = blockIdx.y + 1;                // 1..11
    const int b   = blockIdx.z;
    const int m0  = mt * MROWS;
    const float inv_f = 0.17677669529663687f;      // 1/sqrt(32)

    const float* xp_src = (t == 1) ? x0 : xcur;

    // stage all of X_t into LDS (fp16-packed)
    #pragma unroll
    for (int p = 0; p < 16; ++p) {
        int idx = tid + 256 * p;                   // 0..4095 float4-groups
        int row = idx >> 3;
        int q   = idx & 7;
        float4 v = *reinterpret_cast<const float4*>(&xcur[xidx(b, row, t, q * 4)]);
        Xt[row][2 * q]     = packh2(v.x, v.y);
        Xt[row][2 * q + 1] = packh2(v.z, v.w);
    }

    // x_pred partial accumulator: thread owns 8 n x 8 f
    const int jf = tid & 3;
    const int f0 = jf * 8;
    const int kn = tid >> 2;                       // 0..63
    float acc[8][8];
    #pragma unroll
    for (int i = 0; i < 8; ++i)
        #pragma unroll
        for (int ff = 0; ff < 8; ++ff) acc[i][ff] = 0.f;

    const int pbase = ((b * T_ + t) * N_) * N_;

    for (int c = 0; c < NCHUNK; ++c) {
        const int mg0 = m0 + c * CH;
        __syncthreads();   // Xt ready / previous chunk's Sch,Xp reads done

        // scores S[8][512]: each wave handles 2 rows over all 512 cols
        {
            const int tm = tid >> 6;               // 0..3 (wave-uniform)
            const int tn = tid & 63;
            float s0[8], s1[8];
            #pragma unroll
            for (int i = 0; i < 8; ++i) { s0[i] = 0.f; s1[i] = 0.f; }
            #pragma unroll
            for (int fp = 0; fp < 16; ++fp) {
                f16x2 a0 = u2h(Xt[mg0 + tm * 2 + 0][fp]);
                f16x2 a1 = u2h(Xt[mg0 + tm * 2 + 1][fp]);
                #pragma unroll
                for (int i = 0; i < 8; ++i) {
                    f16x2 bb = u2h(Xt[tn + 64 * i][fp]);
                    s0[i] = __builtin_amdgcn_fdot2(a0, bb, s0[i], false);
                    s1[i] = __builtin_amdgcn_fdot2(a1, bb, s1[i], false);
                }
            }
            #pragma unroll
            for (int i = 0; i < 8; ++i) {
                Sch[tm * 2 + 0][tn + 64 * i] = s0[i] * inv_f;
                Sch[tm * 2 + 1][tn + 64 * i] = s1[i] * inv_f;
            }
        }
        // stage prev-time rows for this chunk (fp32)
        if (tid < 64) {
            int r = tid >> 3, q = tid & 7;
            float4 v = *reinterpret_cast<const float4*>(&xp_src[xidx(b, mg0 + r, t - 1, q * 4)]);
            *reinterpret_cast<float4*>(&Xp[r][q * 4]) = v;
        }
        __syncthreads();

        // row softmax stats (row = 32 lanes)
        {
            const int r  = tid >> 5;               // 0..7
            const int cc = tid & 31;
            float mx = -3.0e38f;
            #pragma unroll
            for (int j = 0; j < 16; ++j) mx = fmaxf(mx, Sch[r][cc + 32 * j]);
            #pragma unroll
            for (int d = 1; d < 32; d <<= 1) mx = fmaxf(mx, __shfl_xor(mx, d, 64));
            float sm = 0.f;
            #pragma unroll
            for (int j = 0; j < 16; ++j) sm += __expf(Sch[r][cc + 32 * j] - mx);
            #pragma unroll
            for (int d = 1; d < 32; d <<= 1) sm += __shfl_xor(sm, d, 64);
            if (cc == 0) { smax[r] = mx; srcp[r] = inv_f / sm; }  // fold inv_sqrt_f
        }
        __syncthreads();

        // W[m][n] = softmax * inv_f * phase[b,t,m,n]   (in place in Sch)
        {
            const float* ph = phase + pbase;
            #pragma unroll
            for (int p = 0; p < 16; ++p) {
                int idx = tid + 256 * p;           // 0..4095
                int m = idx >> 9;
                int n = idx & 511;
                Sch[m][n] = __expf(Sch[m][n] - smax[m]) * srcp[m] * ph[(mg0 + m) * N_ + n];
            }
        }
        __syncthreads();

        // x_pred[n,f] += sum_m W[m,n] * Xprev[m,f]
        #pragma unroll
        for (int m = 0; m < CH; ++m) {
            float4 xa = *reinterpret_cast<const float4*>(&Xp[m][f0]);
            float4 xb = *reinterpret_cast<const float4*>(&Xp[m][f0 + 4]);
            #pragma unroll
            for (int i = 0; i < 8; ++i) {
                float w = Sch[m][kn + 64 * i];
                acc[i][0] += w * xa.x; acc[i][1] += w * xa.y;
                acc[i][2] += w * xa.z; acc[i][3] += w * xa.w;
                acc[i][4] += w * xb.x; acc[i][5] += w * xb.y;
                acc[i][6] += w * xb.z; acc[i][7] += w * xb.w;
            }
        }
    }

    // unmasked nodes: atomic-reduce partials
    #pragma unroll
    for (int i = 0; i < 8; ++i) {
        int n = kn + 64 * i;
        if (mask[n] == 0.f) {
            float* dst = &xnext[xidx(b, n, t, f0)];
            #pragma unroll
            for (int ff = 0; ff < 8; ++ff) atomAddF(&dst[ff], acc[i][ff]);
        }
    }
    // masked nodes: passthrough (single writer: mt==0)
    if (mt == 0) {
        #pragma unroll
        for (int p = 0; p < 64; ++p) {
            int idx = tid + 256 * p;               // 0..16383
            int n = idx >> 5;
            int f = idx & 31;
            if (mask[n] != 0.f) xnext[xidx(b, n, t, f)] = xcur[xidx(b, n, t, f)];
        }
    }
}

// Final aggregation: agg[b,t,n,f] = sum_m phase*adj*sa[m,n] * x[b,m,t,f]
__global__ __launch_bounds__(256)
void final_agg_kernel(const float* __restrict__ x0,
                      const float* __restrict__ xcur,
                      float* __restrict__ agg,     // pre-zeroed, layout [B][T][N][F]
                      const float* __restrict__ phase,
                      const float* __restrict__ adjm)
{
    __shared__ uint_t Xt[N_][17];
    __shared__ float Sch[CH][PAD_S];
    __shared__ float smax[CH];
    __shared__ float srcp[CH];

    const int tid = threadIdx.x;
    const int mt  = blockIdx.x;
    const int t   = blockIdx.y;                    // 0..11
    const int b   = blockIdx.z;
    const int m0  = mt * MROWS;
    const float inv_f = 0.17677669529663687f;

    const float* xs = (t == 0) ? x0 : xcur;

    #pragma unroll
    for (int p = 0; p < 16; ++p) {
        int idx = tid + 256 * p;
        int row = idx >> 3;
        int q   = idx & 7;
        float4 v = *reinterpret_cast<const float4*>(&xs[xidx(b, row, t, q * 4)]);
        Xt[row][2 * q]     = packh2(v.x, v.y);
        Xt[row][2 * q + 1] = packh2(v.z, v.w);
    }

    const int jf = tid & 3;
    const int f0 = jf * 8;
    const int kn = tid >> 2;
    float acc[8][8];
    #pragma unroll
    for (int i = 0; i < 8; ++i)
        #pragma unroll
        for (int ff = 0; ff < 8; ++ff) acc[i][ff] = 0.f;

    const int pbase = ((b * T_ + t) * N_) * N_;

    for (int c = 0; c < NCHUNK; ++c) {
        const int mg0 = m0 + c * CH;
        __syncthreads();
        {
            const int tm = tid >> 6;
            const int tn = tid & 63;
            float s0[8], s1[8];
            #pragma unroll
            for (int i = 0; i < 8; ++i) { s0[i] = 0.f; s1[i] = 0.f; }
            #pragma unroll
            for (int fp = 0; fp < 16; ++fp) {
                f16x2 a0 = u2h(Xt[mg0 + tm * 2 + 0][fp]);
                f16x2 a1 = u2h(Xt[mg0 + tm * 2 + 1][fp]);
                #pragma unroll
                for (int i = 0; i < 8; ++i) {
                    f16x2 bb = u2h(Xt[tn + 64 * i][fp]);
                    s0[i] = __builtin_amdgcn_fdot2(a0, bb, s0[i], false);
                    s1[i] = __builtin_amdgcn_fdot2(a1, bb, s1[i], false);
                }
            }
            #pragma unroll
            for (int i = 0; i < 8; ++i) {
                Sch[tm * 2 + 0][tn + 64 * i] = s0[i] * inv_f;
                Sch[tm * 2 + 1][tn + 64 * i] = s1[i] * inv_f;
            }
        }
        __syncthreads();
        {
            const int r  = tid >> 5;
            const int cc = tid & 31;
            float mx = -3.0e38f;
            #pragma unroll
            for (int j = 0; j < 16; ++j) mx = fmaxf(mx, Sch[r][cc + 32 * j]);
            #pragma unroll
            for (int d = 1; d < 32; d <<= 1) mx = fmaxf(mx, __shfl_xor(mx, d, 64));
            float sm = 0.f;
            #pragma unroll
            for (int j = 0; j < 16; ++j) sm += __expf(Sch[r][cc + 32 * j] - mx);
            #pragma unroll
            for (int d = 1; d < 32; d <<= 1) sm += __shfl_xor(sm, d, 64);
            if (cc == 0) { smax[r] = mx; srcp[r] = inv_f / sm; }
        }
        __syncthreads();
        {
            const float* ph = phase + pbase;
            #pragma unroll
            for (int p = 0; p < 16; ++p) {
                int idx = tid + 256 * p;
                int m = idx >> 9;
                int n = idx & 511;
                int gi = (mg0 + m) * N_ + n;
                Sch[m][n] = __expf(Sch[m][n] - smax[m]) * srcp[m] * ph[gi] * adjm[gi];
            }
        }
        __syncthreads();
        #pragma unroll
        for (int m = 0; m < CH; ++m) {
            f16x2 h0 = u2h(Xt[mg0 + m][jf * 4 + 0]);
            f16x2 h1 = u2h(Xt[mg0 + m][jf * 4 + 1]);
            f16x2 h2 = u2h(Xt[mg0 + m][jf * 4 + 2]);
            f16x2 h3 = u2h(Xt[mg0 + m][jf * 4 + 3]);
            float xv0 = (float)h0[0], xv1 = (float)h0[1], xv2 = (float)h1[0], xv3 = (float)h1[1];
            float xv4 = (float)h2[0], xv5 = (float)h2[1], xv6 = (float)h3[0], xv7 = (float)h3[1];
            #pragma unroll
            for (int i = 0; i < 8; ++i) {
                float w = Sch[m][kn + 64 * i];
                acc[i][0] += w * xv0; acc[i][1] += w * xv1;
                acc[i][2] += w * xv2; acc[i][3] += w * xv3;
                acc[i][4] += w * xv4; acc[i][5] += w * xv5;
                acc[i][6] += w * xv6; acc[i][7] += w * xv7;
            }
        }
    }

    #pragma unroll
    for (int i = 0; i < 8; ++i) {
        int n = kn + 64 * i;
        float* dst = &agg[((b * T_ + t) * N_ + n) * F_ + f0];
        #pragma unroll
        for (int ff = 0; ff < 8; ++ff) atomAddF(&dst[ff], acc[i][ff]);
    }
}

// out[b,n,t,o] = relu(sum_f agg[b,t,n,f] * theta[f,o]), fp32 store
__global__ __launch_bounds__(256)
void proj_kernel(const float* __restrict__ agg, const float* __restrict__ theta,
                 float* __restrict__ out)
{
    __shared__ float th[F_ * O_];
    int tid = threadIdx.x;
    #pragma unroll
    for (int p = 0; p < 8; ++p) th[tid + 256 * p] = theta[tid + 256 * p];
    __syncthreads();
    int g = blockIdx.x * 256 + tid;                // == ((b*N+n)*T+t)*O+o
    int o  = g & 63;
    int r  = g >> 6;
    int tt = r % T_;
    int r2 = r / T_;
    int n  = r2 & 511;
    int b  = r2 >> 9;
    const float* a = &agg[((b * T_ + tt) * N_ + n) * F_];
    float s = 0.f;
    #pragma unroll
    for (int f = 0; f < F_; ++f) s += a[f] * th[f * O_ + o];
    out[g] = fmaxf(s, 0.f);
}

extern "C" void kernel_launch(void* const* d_in, const int* in_sizes, int n_in,
                              void* d_out, int out_size, void* d_ws, size_t ws_size,
                              hipStream_t stream)
{
    const float* x     = (const float*)d_in[0];
    const float* phase = (const float*)d_in[1];
    const float* adj   = (const float*)d_in[2];
    const float* mask  = (const float*)d_in[3];
    const float* theta = (const float*)d_in[4];
    float* out = (float*)d_out;

    const size_t XE = (size_t)B_ * N_ * T_ * F_;   // 1,572,864
    float* xA  = (float*)d_ws;
    float* xB  = xA + XE;
    float* agg = xB + XE;                          // total ws: 3*XE*4B = 18.9 MB

    const float* cur = x;
    float* bufs[2] = { xA, xB };
    for (int i = 0; i < T_ - 1; ++i) {             // 11 fixed-point iterations
        float* nxt = bufs[i & 1];
        hipMemsetAsync(nxt, 0, XE * sizeof(float), stream);
        iter_kernel<<<dim3(MT, T_ - 1, B_), 256, 0, stream>>>(x, cur, nxt, phase, mask);
        cur = nxt;
    }
    hipMemsetAsync(agg, 0, XE * sizeof(float), stream);
    final_agg_kernel<<<dim3(MT, T_, B_), 256, 0, stream>>>(x, cur, agg, phase, adj);
    proj_kernel<<<(B_ * N_ * T_ * O_) / 256, 256, 0, stream>>>(agg, theta, out);
}

// Round 3
// 893.384 us; speedup vs baseline: 4.1045x; 4.1045x over previous
//
#include <hip/hip_runtime.h>

// spatialAttentionScaledGCN — MI355X MFMA version.
// B=8, N=512, T=12, F=32, O=64. All I/O fp32.
// Per (b,t): S = X_t·X_tᵀ·inv_f  (mfma 16x16x32_f16, K=32=F, no K-loop),
// row-softmax over n (cross-wave stats via 2KB LDS, 1 barrier/chunk),
// W = sa·inv_f·phase (fp16, in C-layout regs == A-layout of Wᵀ for K=16 MFMA),
// x_pred += Wᵀ·X_prev (mfma 16x16x16f16), atomic-reduced over m-splits.
// Phase pre-permuted to MFMA lane order as fp16 (coalesced dwordx2 loads).

#define B_ 8
#define N_ 512
#define T_ 12
#define F_ 32
#define O_ 64
#define MT 4                    // m-splits per (b,t); block owns 128 m-rows
#define NW 8                    // waves per block (512 threads)

typedef unsigned int uint_t;
typedef unsigned short ushort_t;
typedef _Float16 f16_t;
typedef _Float16 f16x4 __attribute__((ext_vector_type(4)));
typedef _Float16 f16x8 __attribute__((ext_vector_type(8)));
typedef float f32x4 __attribute__((ext_vector_type(4)));

__device__ __forceinline__ void atomAddF(float* p, float v) {
    __hip_atomic_fetch_add(p, v, __ATOMIC_RELAXED, __HIP_MEMORY_SCOPE_AGENT);
}
__device__ __forceinline__ int xidx(int b, int n, int t, int f) {
    return ((b * N_ + n) * T_ + t) * F_ + f;
}
// load 8 consecutive fp32, convert to packed f16x8 (one MFMA A/B frag quarter)
__device__ __forceinline__ f16x8 load_frag8(const float* p) {
    float4 a = *reinterpret_cast<const float4*>(p);
    float4 b = *reinterpret_cast<const float4*>(p + 4);
    f16x8 r;
    r[0] = (f16_t)a.x; r[1] = (f16_t)a.y; r[2] = (f16_t)a.z; r[3] = (f16_t)a.w;
    r[4] = (f16_t)b.x; r[5] = (f16_t)b.y; r[6] = (f16_t)b.z; r[7] = (f16_t)b.w;
    return r;
}
union U2H4 { uint2 u; f16x4 h; };

// ---------------------------------------------------------------------------
// Permute one 512x512 fp32 slice into MFMA-lane-order fp16:
// dst halves h = ((mc*32 + nt)*256) + quad*64 + col*4 + j  <=  src[mc*16+quad*4+j][nt*16+col]
// so a consuming lane l=quad*16+col reads its 4 halves with ONE dwordx2.
__global__ __launch_bounds__(256)
void permute_kernel(const float* __restrict__ src, ushort_t* __restrict__ dst)
{
    __shared__ float Lp[16][516];
    const int tid = threadIdx.x;
    const int mc  = blockIdx.x;               // 0..31 row-chunk
    const int s   = blockIdx.y;               // slice (b*12+t for phase; 0 for adj)
    src += (size_t)s * N_ * N_ + (size_t)mc * 16 * N_;
    uint_t* dstu = (uint_t*)dst + (size_t)s * 131072 + (size_t)mc * 4096;

    #pragma unroll
    for (int k = 0; k < 32; ++k) {
        int idx = tid + 256 * k;              // 0..8191
        Lp[idx >> 9][idx & 511] = src[idx];
    }
    __syncthreads();
    #pragma unroll
    for (int k = 0; k < 16; ++k) {
        int u    = tid + 256 * k;             // u32 index 0..4095
        int nt   = u >> 7;
        int r    = u & 127;
        int quad = r >> 5;
        int cl   = (r >> 1) & 15;
        int m0   = quad * 4 + (r & 1) * 2;
        int n    = nt * 16 + cl;
        union { f16_t h[2]; uint_t i; } pk;
        pk.h[0] = (f16_t)Lp[m0][n];
        pk.h[1] = (f16_t)Lp[m0 + 1][n];
        dstu[u] = pk.i;
    }
}

// ---------------------------------------------------------------------------
// One Jacobi iteration step for all (b, t>=1); block = (mt, t-1, b), 512 thr.
// FINAL=1: weight *= adj, Xp = X_t (same t), plain atomic to agg (no mask).
template <int FINAL>
__global__ __launch_bounds__(512)
void gcn_kernel(const float* __restrict__ x0,
                const float* __restrict__ xcur,
                float* __restrict__ dst,            // xnext or agg (pre-zeroed)
                const ushort_t* __restrict__ phase_h,
                const ushort_t* __restrict__ adj_h,
                const float* __restrict__ mask)
{
    __shared__ float2 st[2][NW][16];

    const int tid  = threadIdx.x;
    const int w    = tid >> 6;
    const int l    = tid & 63;
    const int quad = l >> 4;
    const int col  = l & 15;
    const int mt   = blockIdx.x;
    const int t    = FINAL ? blockIdx.y : blockIdx.y + 1;
    const int b    = blockIdx.z;
    const int nt0  = w * 4;                  // wave owns n-tiles nt0..nt0+3
    const float inv_f = 0.17677669529663687f;

    const float* xs     = (FINAL && t == 0) ? x0 : xcur;     // X_t source
    const float* xp_src = FINAL ? xs : ((t == 1) ? x0 : xcur); // pred operand
    const int    tp     = FINAL ? t : t - 1;

    // score B-frags for this wave's 4 n-tiles (fixed across chunks)
    f16x8 bf[4];
    #pragma unroll
    for (int i = 0; i < 4; ++i)
        bf[i] = load_frag8(&xs[xidx(b, (nt0 + i) * 16 + col, t, quad * 8)]);

    f32x4 acc[4][2];
    #pragma unroll
    for (int i = 0; i < 4; ++i) {
        acc[i][0] = (f32x4){0.f, 0.f, 0.f, 0.f};
        acc[i][1] = (f32x4){0.f, 0.f, 0.f, 0.f};
    }

    const uint_t* phu = (const uint_t*)phase_h + (size_t)(b * T_ + t) * 131072;
    const uint_t* adu = (const uint_t*)adj_h;

    for (int c = 0; c < 512 / (MT * 16); ++c) {   // 8 chunks of 16 m-rows
        const int mb = mt * (N_ / MT) + c * 16;
        const int mc = mb >> 4;                   // global chunk index

        // ---- scores: S[16 x 4*16] for this m-chunk ----
        f16x8 af = load_frag8(&xs[xidx(b, mb + col, t, quad * 8)]);
        f32x4 s4[4];
        #pragma unroll
        for (int i = 0; i < 4; ++i) {
            s4[i] = __builtin_amdgcn_mfma_f32_16x16x32_f16(
                        af, bf[i], (f32x4){0.f, 0.f, 0.f, 0.f}, 0, 0, 0);
        }
        // ---- wave-local softmax stats (rows m = quad*4+v, cols = 64 n) ----
        float mxw[4], sw[4], e[4][4];
        #pragma unroll
        for (int v = 0; v < 4; ++v) {
            #pragma unroll
            for (int i = 0; i < 4; ++i) s4[i][v] *= inv_f;
            mxw[v] = fmaxf(fmaxf(s4[0][v], s4[1][v]), fmaxf(s4[2][v], s4[3][v]));
        }
        #pragma unroll
        for (int d = 1; d < 16; d <<= 1)
            #pragma unroll
            for (int v = 0; v < 4; ++v)
                mxw[v] = fmaxf(mxw[v], __shfl_xor(mxw[v], d, 64));
        #pragma unroll
        for (int v = 0; v < 4; ++v) {
            #pragma unroll
            for (int i = 0; i < 4; ++i) e[i][v] = __expf(s4[i][v] - mxw[v]);
            sw[v] = (e[0][v] + e[1][v]) + (e[2][v] + e[3][v]);
        }
        #pragma unroll
        for (int d = 1; d < 16; d <<= 1)
            #pragma unroll
            for (int v = 0; v < 4; ++v)
                sw[v] += __shfl_xor(sw[v], d, 64);

        // ---- cross-wave combine via 2KB LDS (ping-pong, 1 barrier) ----
        const int buf = c & 1;
        if (col < 4) {
            float mv = (col == 0) ? mxw[0] : (col == 1) ? mxw[1] : (col == 2) ? mxw[2] : mxw[3];
            float sv = (col == 0) ? sw[0]  : (col == 1) ? sw[1]  : (col == 2) ? sw[2]  : sw[3];
            st[buf][w][quad * 4 + col] = make_float2(mv, sv);
        }
        __syncthreads();
        {
            const int row = l >> 2, wp = l & 3;
            float2 p0 = st[buf][2 * wp][row];
            float2 p1 = st[buf][2 * wp + 1][row];
            float M = fmaxf(p0.x, p1.x);
            float S = p0.y * __expf(p0.x - M) + p1.y * __expf(p1.x - M);
            #pragma unroll
            for (int d = 1; d < 4; d <<= 1) {
                float Mo = __shfl_xor(M, d, 64), So = __shfl_xor(S, d, 64);
                float Mn = fmaxf(M, Mo);
                S = S * __expf(M - Mn) + So * __expf(Mo - Mn);
                M = Mn;
            }
            #pragma unroll
            for (int v = 0; v < 4; ++v) {
                float Mr = __shfl(M, quad * 16 + v * 4, 64);
                float Sr = __shfl(S, quad * 16 + v * 4, 64);
                // beta = exp(local_max - global_max) * inv_f / global_sum
                e[0][v] *= 1.f;  // keep
                mxw[v] = __expf(mxw[v] - Mr) * inv_f / Sr;   // reuse mxw as beta
            }
        }

        // ---- pred B-frags: Xp[m_local][f], K=16 layout k=quad*4+j ----
        f16x4 bp[2];
        #pragma unroll
        for (int ft = 0; ft < 2; ++ft)
            #pragma unroll
            for (int j = 0; j < 4; ++j)
                bp[ft][j] = (f16_t)xp_src[xidx(b, mb + quad * 4 + j, tp, ft * 16 + col)];

        // ---- W = e*beta*phase(*adj), C-layout == A-layout of W^T; pred MFMA ----
        #pragma unroll
        for (int i = 0; i < 4; ++i) {
            U2H4 ph; ph.u = *(const uint2*)(phu + (size_t)mc * 4096 + (nt0 + i) * 128 + l * 2);
            f16x4 wf;
            if (FINAL) {
                U2H4 aj; aj.u = *(const uint2*)(adu + (size_t)mc * 4096 + (nt0 + i) * 128 + l * 2);
                #pragma unroll
                for (int v = 0; v < 4; ++v)
                    wf[v] = (f16_t)(e[i][v] * mxw[v] * (float)ph.h[v] * (float)aj.h[v]);
            } else {
                #pragma unroll
                for (int v = 0; v < 4; ++v)
                    wf[v] = (f16_t)(e[i][v] * mxw[v] * (float)ph.h[v]);
            }
            #pragma unroll
            for (int ft = 0; ft < 2; ++ft)
                acc[i][ft] = __builtin_amdgcn_mfma_f32_16x16x16f16(wf, bp[ft], acc[i][ft], 0, 0, 0);
        }
    }

    // ---- epilogue: atomic-reduce partial x_pred / agg ----
    #pragma unroll
    for (int i = 0; i < 4; ++i) {
        #pragma unroll
        for (int v = 0; v < 4; ++v) {
            const int n = (nt0 + i) * 16 + quad * 4 + v;
            if (FINAL) {
                float* d0 = &dst[((b * T_ + t) * N_ + n) * F_ + col];
                atomAddF(d0, acc[i][0][v]);
                atomAddF(d0 + 16, acc[i][1][v]);
            } else if (mask[n] == 0.f) {
                atomAddF(&dst[xidx(b, n, t, col)], acc[i][0][v]);
                atomAddF(&dst[xidx(b, n, t, 16 + col)], acc[i][1][v]);
            }
        }
    }
    if (!FINAL && mt == 0) {   // masked passthrough, single writer
        for (int p = tid; p < N_ * F_; p += 512) {
            int n = p >> 5, f = p & 31;
            if (mask[n] != 0.f) dst[xidx(b, n, t, f)] = xcur[xidx(b, n, t, f)];
        }
    }
}

// out[b,n,t,o] = relu(sum_f agg[b,t,n,f] * theta[f,o])
__global__ __launch_bounds__(256)
void proj_kernel(const float* __restrict__ agg, const float* __restrict__ theta,
                 float* __restrict__ out)
{
    __shared__ float th[F_ * O_];
    int tid = threadIdx.x;
    #pragma unroll
    for (int p = 0; p < 8; ++p) th[tid + 256 * p] = theta[tid + 256 * p];
    __syncthreads();
    int g  = blockIdx.x * 256 + tid;           // ((b*N+n)*T+t)*O+o
    int o  = g & 63;
    int r  = g >> 6;
    int tt = r % T_;
    int r2 = r / T_;
    int n  = r2 & 511;
    int b  = r2 >> 9;
    const float* a = &agg[((b * T_ + tt) * N_ + n) * F_];
    float s = 0.f;
    #pragma unroll
    for (int f = 0; f < F_; ++f) s += a[f] * th[f * O_ + o];
    out[g] = fmaxf(s, 0.f);
}

extern "C" void kernel_launch(void* const* d_in, const int* in_sizes, int n_in,
                              void* d_out, int out_size, void* d_ws, size_t ws_size,
                              hipStream_t stream)
{
    const float* x     = (const float*)d_in[0];
    const float* phase = (const float*)d_in[1];
    const float* adj   = (const float*)d_in[2];
    const float* mask  = (const float*)d_in[3];
    const float* theta = (const float*)d_in[4];
    float* out = (float*)d_out;

    const size_t XE = (size_t)B_ * N_ * T_ * F_;       // 1,572,864 floats
    float*    xA      = (float*)d_ws;                  //  6.3 MB
    float*    xB      = xA + XE;                       //  6.3 MB
    float*    agg     = xB + XE;                       //  6.3 MB
    ushort_t* phase_h = (ushort_t*)(agg + XE);         // 50.3 MB (96 slices, f16 permuted)
    ushort_t* adj_h   = phase_h + (size_t)96 * N_ * N_; // 0.5 MB

    permute_kernel<<<dim3(32, 96), 256, 0, stream>>>(phase, phase_h);
    permute_kernel<<<dim3(32, 1), 256, 0, stream>>>(adj, adj_h);

    const float* cur = x;
    float* bufs[2] = { xA, xB };
    for (int i = 0; i < T_ - 1; ++i) {                 // 11 Jacobi iterations
        float* nxt = bufs[i & 1];
        hipMemsetAsync(nxt, 0, XE * sizeof(float), stream);
        gcn_kernel<0><<<dim3(MT, T_ - 1, B_), 512, 0, stream>>>(
            x, cur, nxt, phase_h, adj_h, mask);
        cur = nxt;
    }
    hipMemsetAsync(agg, 0, XE * sizeof(float), stream);
    gcn_kernel<1><<<dim3(MT, T_, B_), 512, 0, stream>>>(
        x, cur, agg, phase_h, adj_h, mask);
    proj_kernel<<<(B_ * N_ * T_ * O_) / 256, 256, 0, stream>>>(agg, theta, out);
}